// Round 2
// baseline (5631.729 us; speedup 1.0000x reference)
//
#include <hip/hip_runtime.h>
#include <math.h>

#define CIN   192
#define C3    576
#define HWSZ  65536   // 256*256

// ---------------------------------------------------------------------------
// K1: fp32 tiled GEMM for qkv 1x1 conv (spatial output).
// ---------------------------------------------------------------------------
__global__ __launch_bounds__(256) void conv1x1_gemm(
    const float* __restrict__ X, const float* __restrict__ Wm,
    float* __restrict__ Y) {
  __shared__ float As[16][68];
  __shared__ float Bs[16][68];
  const int pt = blockIdx.x * 64;
  const int ot = blockIdx.y * 64;
  const int b  = blockIdx.z;
  const int Mout = gridDim.y * 64;
  const float* Xb = X + (size_t)b * CIN * HWSZ;
  float* Yb = Y + (size_t)b * (size_t)Mout * HWSZ;
  const int tid = threadIdx.x;
  const int tx = tid & 15, ty = tid >> 4;
  const int oA = tid >> 2;
  const int kA = (tid & 3) * 4;
  const int kB = tid >> 4;
  const int pB = (tid & 15) * 4;
  float acc[4][4];
#pragma unroll
  for (int i = 0; i < 4; ++i)
#pragma unroll
    for (int j = 0; j < 4; ++j) acc[i][j] = 0.f;

  for (int k0 = 0; k0 < CIN; k0 += 16) {
    float4 av = *(const float4*)(Wm + (size_t)(ot + oA) * CIN + k0 + kA);
    As[kA + 0][oA] = av.x;
    As[kA + 1][oA] = av.y;
    As[kA + 2][oA] = av.z;
    As[kA + 3][oA] = av.w;
    *(float4*)&Bs[kB][pB] =
        *(const float4*)(Xb + (size_t)(k0 + kB) * HWSZ + pt + pB);
    __syncthreads();
#pragma unroll
    for (int k = 0; k < 16; ++k) {
      const float4 a4 = *(const float4*)&As[k][ty * 4];
      const float4 b4 = *(const float4*)&Bs[k][tx * 4];
      const float avr[4] = {a4.x, a4.y, a4.z, a4.w};
      const float bvr[4] = {b4.x, b4.y, b4.z, b4.w};
#pragma unroll
      for (int i = 0; i < 4; ++i)
#pragma unroll
        for (int j = 0; j < 4; ++j) acc[i][j] += avr[i] * bvr[j];
    }
    __syncthreads();
  }
#pragma unroll
  for (int i = 0; i < 4; ++i) {
    const int o = ot + ty * 4 + i;
    float4 r;
    r.x = acc[i][0]; r.y = acc[i][1]; r.z = acc[i][2]; r.w = acc[i][3];
    *(float4*)(Yb + (size_t)o * HWSZ + pt + tx * 4) = r;
  }
}

// ---------------------------------------------------------------------------
// K2: fused dwconv3x3 + windowed channel attention + mlp gate.
// One block per (win, head, b), XCD-swizzled so consecutive windows share an
// XCD L2 (halo reuse). dwv is channel-major [gc][t] stride 68 so every hot
// phase uses ds_read_b128 / ds_write_b128.
// Logits thread (c,m) covers k-columns {m, m+8, m+16, m+24}: k-row LDS bank
// index = (4m+tt)%32 -> 8 m-lanes spread over all 32 banks (conflict-free).
// ---------------------------------------------------------------------------
__global__ __launch_bounds__(256, 3) void attn_fused2(
    const float* __restrict__ qkv, const float* __restrict__ wdw,
    const float* __restrict__ temp, const float* __restrict__ mlpw,
    const float* __restrict__ mlpb, float* __restrict__ yw) {
  __shared__ float smB[64 * 68];   // staging (32*101 used), then mwT [x][y]
  __shared__ float dwv[96 * 68];   // [gc][t]: q 0..31, k 32..63, v 64..95
  __shared__ float attnS[32 * 33];
  __shared__ float scl[64];
  const int bid = blockIdx.x;
  const int b   = bid / 6144;
  const int rr  = bid % 6144;
  const int xcd = rr & 7;
  const int s   = rr >> 3;
  const int head = s % 6;
  const int wloc = s / 6;
  const int win  = xcd * 128 + wloc;
  const int h1 = win >> 5, w1 = win & 31;
  const int tid = threadIdx.x;
  const int ch = tid >> 3;   // 0..31
  const int iy = tid & 7;    // 0..7

  // ---- staging + depthwise conv, per qkv group ----
  const int row0 = h1 * 8 - 1, col0 = w1 * 8 - 1;
  for (int g = 0; g < 3; ++g) {
    __syncthreads();
    const size_t cbase = (size_t)b * C3 + g * 192 + head * 32;
    for (int idx = tid; idx < 3200; idx += 256) {
      const int c = idx / 100, rem = idx - c * 100;
      const int yy = rem / 10, xx = rem - yy * 10;
      const int gy = row0 + yy, gx = col0 + xx;
      float v = 0.f;
      if ((unsigned)gy < 256u && (unsigned)gx < 256u)
        v = qkv[((cbase + c) * 256 + gy) * 256 + gx];
      smB[c * 101 + rem] = v;
    }
    __syncthreads();
    const float* w9 = wdw + (size_t)(g * 192 + head * 32 + ch) * 9;
    const float w0 = w9[0], w1_ = w9[1], w2 = w9[2];
    const float w3 = w9[3], w4 = w9[4], w5 = w9[5];
    const float w6 = w9[6], w7 = w9[7], w8 = w9[8];
    const float* t0 = &smB[ch * 101 + iy * 10];
    float rv[8];
#pragma unroll
    for (int ix = 0; ix < 8; ++ix) {
      rv[ix] = t0[ix] * w0 + t0[ix + 1] * w1_ + t0[ix + 2] * w2
             + t0[10 + ix] * w3 + t0[11 + ix] * w4 + t0[12 + ix] * w5
             + t0[20 + ix] * w6 + t0[21 + ix] * w7 + t0[22 + ix] * w8;
    }
    float* dp = &dwv[(g * 32 + ch) * 68 + iy * 8];
    *(float4*)dp       = make_float4(rv[0], rv[1], rv[2], rv[3]);
    *(float4*)(dp + 4) = make_float4(rv[4], rv[5], rv[6], rv[7]);
  }
  __syncthreads();   // dwv complete; smB free for mwT

  // ---- mlp weights transposed into smB; l2norm scales ----
  for (int e = tid; e < 4096; e += 256)
    smB[(e & 63) * 68 + (e >> 6)] = mlpw[e];
  if (tid < 64) {
    float ss = 0.f;
    const float* r = &dwv[tid * 68];
    for (int tt = 0; tt < 64; tt += 4) {
      const float4 v = *(const float4*)(r + tt);
      ss += v.x * v.x + v.y * v.y + v.z * v.z + v.w * v.w;
    }
    scl[tid] = 1.f / fmaxf(sqrtf(ss), 1e-12f);
  }
  __syncthreads();

  // ---- logits + softmax ----
  {
    const int c = tid >> 3, m = tid & 7;
    float s0 = 0.f, s1 = 0.f, s2 = 0.f, s3 = 0.f;
    const float* qr = &dwv[c * 68];
    const float* kb = &dwv[32 * 68];
    for (int tt = 0; tt < 64; tt += 4) {
      const float4 q  = *(const float4*)(qr + tt);
      const float4 ka = *(const float4*)(kb + m * 68 + tt);
      const float4 k1 = *(const float4*)(kb + (m + 8) * 68 + tt);
      const float4 k2 = *(const float4*)(kb + (m + 16) * 68 + tt);
      const float4 k3 = *(const float4*)(kb + (m + 24) * 68 + tt);
      s0 += q.x * ka.x + q.y * ka.y + q.z * ka.z + q.w * ka.w;
      s1 += q.x * k1.x + q.y * k1.y + q.z * k1.z + q.w * k1.w;
      s2 += q.x * k2.x + q.y * k2.y + q.z * k2.z + q.w * k2.w;
      s3 += q.x * k3.x + q.y * k3.y + q.z * k3.z + q.w * k3.w;
    }
    const float qs = scl[c] * temp[head];
    s0 *= qs * scl[32 + m];
    s1 *= qs * scl[32 + m + 8];
    s2 *= qs * scl[32 + m + 16];
    s3 *= qs * scl[32 + m + 24];
    float mx = fmaxf(fmaxf(s0, s1), fmaxf(s2, s3));
    for (int off = 1; off < 8; off <<= 1) mx = fmaxf(mx, __shfl_xor(mx, off, 8));
    s0 = expf(s0 - mx);
    s1 = expf(s1 - mx);
    s2 = expf(s2 - mx);
    s3 = expf(s3 - mx);
    float sum = s0 + s1 + s2 + s3;
    for (int off = 1; off < 8; off <<= 1) sum += __shfl_xor(sum, off, 8);
    const float inv = 1.f / sum;
    attnS[c * 33 + m]      = s0 * inv;
    attnS[c * 33 + m + 8]  = s1 * inv;
    attnS[c * 33 + m + 16] = s2 * inv;
    attnS[c * 33 + m + 24] = s3 * inv;
  }
  __syncthreads();

  // ---- out = attn@v ; gate = GELU(v@mlp^T + b) ; y = out*gate ----
  {
    const int c = tid >> 3, y8 = tid & 7;
    float o0 = 0.f, o1 = 0.f, o2 = 0.f, o3 = 0.f;
    float o4 = 0.f, o5 = 0.f, o6 = 0.f, o7 = 0.f;
    const float* vb = &dwv[64 * 68 + y8 * 8];
    const float* as = &attnS[c * 33];
    for (int d = 0; d < 32; ++d) {
      const float a = as[d];
      const float4 x0 = *(const float4*)(vb + d * 68);
      const float4 x1 = *(const float4*)(vb + d * 68 + 4);
      o0 += a * x0.x; o1 += a * x0.y; o2 += a * x0.z; o3 += a * x0.w;
      o4 += a * x1.x; o5 += a * x1.y; o6 += a * x1.z; o7 += a * x1.w;
    }
    float g0 = mlpb[y8 * 8 + 0], g1 = mlpb[y8 * 8 + 1];
    float g2 = mlpb[y8 * 8 + 2], g3 = mlpb[y8 * 8 + 3];
    float g4 = mlpb[y8 * 8 + 4], g5 = mlpb[y8 * 8 + 5];
    float g6 = mlpb[y8 * 8 + 6], g7 = mlpb[y8 * 8 + 7];
    const float* vc = &dwv[(64 + c) * 68];
    const float* mb = &smB[y8 * 8];
    for (int x = 0; x < 64; ++x) {
      const float vv = vc[x];
      const float4 m0 = *(const float4*)(mb + x * 68);
      const float4 m1 = *(const float4*)(mb + x * 68 + 4);
      g0 += vv * m0.x; g1 += vv * m0.y; g2 += vv * m0.z; g3 += vv * m0.w;
      g4 += vv * m1.x; g5 += vv * m1.y; g6 += vv * m1.z; g7 += vv * m1.w;
    }
    const float kE = 0.70710678118654752f;
    const float r0 = o0 * (0.5f * g0 * (1.f + erff(g0 * kE)));
    const float r1 = o1 * (0.5f * g1 * (1.f + erff(g1 * kE)));
    const float r2 = o2 * (0.5f * g2 * (1.f + erff(g2 * kE)));
    const float r3 = o3 * (0.5f * g3 * (1.f + erff(g3 * kE)));
    const float r4 = o4 * (0.5f * g4 * (1.f + erff(g4 * kE)));
    const float r5 = o5 * (0.5f * g5 * (1.f + erff(g5 * kE)));
    const float r6 = o6 * (0.5f * g6 * (1.f + erff(g6 * kE)));
    const float r7 = o7 * (0.5f * g7 * (1.f + erff(g7 * kE)));
    float* dst = yw + (((size_t)(b * 1024 + win) * 192 + head * 32 + c) * 64
                       + y8 * 8);
    *(float4*)dst       = make_float4(r0, r1, r2, r3);
    *(float4*)(dst + 4) = make_float4(r4, r5, r6, r7);
  }
}

// ---------------------------------------------------------------------------
// K3: proj GEMM reading windowed yw, writing spatial out (+bias).
// ---------------------------------------------------------------------------
__global__ __launch_bounds__(256) void proj_gemm(
    const float* __restrict__ yw, const float* __restrict__ Wm,
    const float* __restrict__ bias, float* __restrict__ out) {
  __shared__ float As[16][68];
  __shared__ float Bs[16][256];
  const int ptile = blockIdx.x;
  const int ot = blockIdx.y * 64;
  const int b  = blockIdx.z;
  const int h1 = ptile >> 3, w4 = ptile & 7;
  const int win0 = h1 * 32 + w4 * 4;
  const int tid = threadIdx.x;
  const int tx = tid & 15, ty = tid >> 4;
  const int oA = tid >> 2, kA = (tid & 3) * 4;
  float acc[4][16];
#pragma unroll
  for (int i = 0; i < 4; ++i)
#pragma unroll
    for (int j = 0; j < 16; ++j) acc[i][j] = 0.f;

  const float* ywb = yw + (size_t)(b * 1024 + win0) * 192 * 64;
  for (int k0 = 0; k0 < 192; k0 += 16) {
    float4 av = *(const float4*)(Wm + (size_t)(ot + oA) * 192 + k0 + kA);
    As[kA + 0][oA] = av.x;
    As[kA + 1][oA] = av.y;
    As[kA + 2][oA] = av.z;
    As[kA + 3][oA] = av.w;
#pragma unroll
    for (int i = 0; i < 4; ++i) {
      const int f4 = tid + 256 * i;
      const int k = f4 >> 6, p4 = f4 & 63;
      const int wv = p4 >> 4, tt = (p4 & 15) * 4;
      *(float4*)&Bs[k][p4 * 4] =
          *(const float4*)(ywb + ((size_t)wv * 192 + k0 + k) * 64 + tt);
    }
    __syncthreads();
#pragma unroll
    for (int k = 0; k < 16; ++k) {
      const float a0 = As[k][ty * 4 + 0];
      const float a1 = As[k][ty * 4 + 1];
      const float a2 = As[k][ty * 4 + 2];
      const float a3 = As[k][ty * 4 + 3];
#pragma unroll
      for (int j = 0; j < 16; ++j) {
        const float bv = Bs[k][tx + 16 * j];
        acc[0][j] += a0 * bv;
        acc[1][j] += a1 * bv;
        acc[2][j] += a2 * bv;
        acc[3][j] += a3 * bv;
      }
    }
    __syncthreads();
  }
  const int colbase = w4 * 32;
#pragma unroll
  for (int i = 0; i < 4; ++i) {
    const int o = ot + ty * 4 + i;
    const float bv = bias[o];
    float* ob = out + ((size_t)(b * 192 + o) * 256 + h1 * 8) * 256 + colbase;
#pragma unroll
    for (int j = 0; j < 16; ++j) {
      const int p = tx + 16 * j;
      const int wv = p >> 6;
      const int t = p & 63;
      ob[(t >> 3) * 256 + wv * 8 + (t & 7)] = acc[i][j] + bv;
    }
  }
}

extern "C" void kernel_launch(void* const* d_in, const int* in_sizes, int n_in,
                              void* d_out, int out_size, void* d_ws, size_t ws_size,
                              hipStream_t stream) {
  const float* x           = (const float*)d_in[0];
  const float* w_qkv       = (const float*)d_in[1];
  const float* w_dw        = (const float*)d_in[2];
  const float* temperature = (const float*)d_in[3];
  const float* mlp_w       = (const float*)d_in[4];
  const float* mlp_b       = (const float*)d_in[5];
  const float* proj_w      = (const float*)d_in[6];
  const float* proj_b      = (const float*)d_in[7];
  float* out = (float*)d_out;

  // Workspace: spatial qkv (302 MB) + windowed yw (100 MB) = 402.65 MB —
  // same footprint as the verified round-0 fallback path.
  const size_t szA = (size_t)2 * C3 * HWSZ;
  float* qkvbuf = (float*)d_ws;
  float* ywbuf  = qkvbuf + szA;

  conv1x1_gemm<<<dim3(1024, 9, 2), 256, 0, stream>>>(x, w_qkv, qkvbuf);
  attn_fused2<<<dim3(12288), 256, 0, stream>>>(qkvbuf, w_dw, temperature,
                                               mlp_w, mlp_b, ywbuf);
  proj_gemm<<<dim3(256, 3, 2), 256, 0, stream>>>(ywbuf, proj_w, proj_b, out);
}

// Round 3
// 1747.962 us; speedup vs baseline: 3.2219x; 3.2219x over previous
//
#include <hip/hip_runtime.h>
#include <math.h>

#define CIN   192
#define C3    576
#define HWSZ  65536   // 256*256

// ---------------------------------------------------------------------------
// K1: fp32 tiled GEMM for qkv 1x1 conv (spatial output, one 192-ch group).
// Mout derived from gridDim.y (grid.y=3 -> 192 output channels).
// ---------------------------------------------------------------------------
__global__ __launch_bounds__(256) void conv1x1_gemm(
    const float* __restrict__ X, const float* __restrict__ Wm,
    float* __restrict__ Y) {
  __shared__ float As[16][68];
  __shared__ float Bs[16][68];
  const int pt = blockIdx.x * 64;
  const int ot = blockIdx.y * 64;
  const int b  = blockIdx.z;
  const int Mout = gridDim.y * 64;
  const float* Xb = X + (size_t)b * CIN * HWSZ;
  float* Yb = Y + (size_t)b * (size_t)Mout * HWSZ;
  const int tid = threadIdx.x;
  const int tx = tid & 15, ty = tid >> 4;
  const int oA = tid >> 2;
  const int kA = (tid & 3) * 4;
  const int kB = tid >> 4;
  const int pB = (tid & 15) * 4;
  float acc[4][4];
#pragma unroll
  for (int i = 0; i < 4; ++i)
#pragma unroll
    for (int j = 0; j < 4; ++j) acc[i][j] = 0.f;

  for (int k0 = 0; k0 < CIN; k0 += 16) {
    float4 av = *(const float4*)(Wm + (size_t)(ot + oA) * CIN + k0 + kA);
    As[kA + 0][oA] = av.x;
    As[kA + 1][oA] = av.y;
    As[kA + 2][oA] = av.z;
    As[kA + 3][oA] = av.w;
    *(float4*)&Bs[kB][pB] =
        *(const float4*)(Xb + (size_t)(k0 + kB) * HWSZ + pt + pB);
    __syncthreads();
#pragma unroll
    for (int k = 0; k < 16; ++k) {
      const float4 a4 = *(const float4*)&As[k][ty * 4];
      const float4 b4 = *(const float4*)&Bs[k][tx * 4];
      const float avr[4] = {a4.x, a4.y, a4.z, a4.w};
      const float bvr[4] = {b4.x, b4.y, b4.z, b4.w};
#pragma unroll
      for (int i = 0; i < 4; ++i)
#pragma unroll
        for (int j = 0; j < 4; ++j) acc[i][j] += avr[i] * bvr[j];
    }
    __syncthreads();
  }
#pragma unroll
  for (int i = 0; i < 4; ++i) {
    const int o = ot + ty * 4 + i;
    float4 r;
    r.x = acc[i][0]; r.y = acc[i][1]; r.z = acc[i][2]; r.w = acc[i][3];
    *(float4*)(Yb + (size_t)o * HWSZ + pt + tx * 4) = r;
  }
}

// ---------------------------------------------------------------------------
// K2a: depthwise 3x3 conv for one 192-channel group (slice layout
// [b][192][HWSZ]). One block per (slice-channel gc, window-row h1, batch).
// Reads full 256-col contiguous rows, writes windowed layout:
// Bw[((b*1024+win)*576 + gbase+gc)*64 + t].
// LDS tile stride 264, payload at col-offset 4 so float4 stores are
// 16B-aligned (spatial col c <-> index c+4; zero pads at 3 and 260).
// (Verified fast in round-1: ~38 us per launch.)
// ---------------------------------------------------------------------------
__global__ __launch_bounds__(256) void dwconv_win(
    const float* __restrict__ qkv, const float* __restrict__ wdw,
    float* __restrict__ Bw, int gbase) {
  __shared__ float t[10][264];
  const int gc = blockIdx.x;     // 0..191 within slice
  const int h1 = blockIdx.y;     // 0..31
  const int b  = blockIdx.z;
  const int tid = threadIdx.x;
  const int r0 = h1 * 8 - 1;
  const float* src = qkv + ((size_t)b * 192 + gc) * HWSZ;

  for (int idx = tid; idx < 640; idx += 256) {
    const int row = idx >> 6, cv = idx & 63;
    const int gr = r0 + row;
    float4 v = make_float4(0.f, 0.f, 0.f, 0.f);
    if ((unsigned)gr < 256u) v = *(const float4*)(src + gr * 256 + cv * 4);
    *(float4*)&t[row][4 + cv * 4] = v;
  }
  if (tid < 10) { t[tid][3] = 0.f; t[tid][260] = 0.f; }
  __syncthreads();

  const float* w9 = wdw + (size_t)(gbase + gc) * 9;
  const float w0 = w9[0], w1 = w9[1], w2 = w9[2];
  const float w3 = w9[3], w4 = w9[4], w5 = w9[5];
  const float w6 = w9[6], w7 = w9[7], w8 = w9[8];

  const int c = tid;                  // spatial col 0..255
  const int wv = c >> 3, tt = c & 7;  // window-in-row, token-col
  float* rec = Bw + (((size_t)(b * 1024 + h1 * 32 + wv) * C3) + gbase + gc) * 64
               + tt;

  float x0 = t[0][c + 3], x1 = t[0][c + 4], x2 = t[0][c + 5];
  float y0 = t[1][c + 3], y1 = t[1][c + 4], y2 = t[1][c + 5];
#pragma unroll
  for (int rr = 1; rr <= 8; ++rr) {
    const float z0 = t[rr + 1][c + 3], z1 = t[rr + 1][c + 4],
                z2 = t[rr + 1][c + 5];
    const float res = x0 * w0 + x1 * w1 + x2 * w2
                    + y0 * w3 + y1 * w4 + y2 * w5
                    + z0 * w6 + z1 * w7 + z2 * w8;
    rec[(rr - 1) * 8] = res;
    x0 = y0; x1 = y1; x2 = y2;
    y0 = z0; y1 = z1; y2 = z2;
  }
}

// ---------------------------------------------------------------------------
// K2b: windowed channel attention + mlp gate.
// Compute phases are VERBATIM from the round-0 harness-verified attn_fused
// (token-major dwv stride 97, scalar LDS reads). Only the staging phase
// differs: dwv is filled from the windowed Bw buffer with fully-coalesced
// float4 reads (2 KB contiguous per wave) and 2-way-bank scalar LDS writes.
// ---------------------------------------------------------------------------
__global__ __launch_bounds__(256, 3) void attn_bw(
    const float* __restrict__ Bw, const float* __restrict__ temp,
    const float* __restrict__ mlpw, const float* __restrict__ mlpb,
    float* __restrict__ yw) {
  __shared__ float smA[4160];
  __shared__ float dwv[64 * 97];
  __shared__ float attnS[32 * 33];
  __shared__ float scl[64];
  const int bid = blockIdx.x;
  const int b   = bid / 6144;
  const int rr  = bid % 6144;
  const int xcd = rr & 7;
  const int s   = rr >> 3;
  const int head = s % 6;
  const int wloc = s / 6;
  const int win  = xcd * 128 + wloc;
  const int tid = threadIdx.x;
  const int ch = tid >> 3;   // 0..31
  const int iy = tid & 7;    // 0..7

  // ---- staging: windowed Bw -> token-major dwv [t*97 + gc] ----
  {
    const float* rec = Bw + (size_t)(b * 1024 + win) * C3 * 64;
    const int t8 = iy * 8;
#pragma unroll
    for (int g = 0; g < 3; ++g) {
      const float* sp = rec + (size_t)(g * 192 + head * 32 + ch) * 64 + t8;
      const float4 v0 = *(const float4*)sp;
      const float4 v1 = *(const float4*)(sp + 4);
      const int gc = g * 32 + ch;
      dwv[(t8 + 0) * 97 + gc] = v0.x;
      dwv[(t8 + 1) * 97 + gc] = v0.y;
      dwv[(t8 + 2) * 97 + gc] = v0.z;
      dwv[(t8 + 3) * 97 + gc] = v0.w;
      dwv[(t8 + 4) * 97 + gc] = v1.x;
      dwv[(t8 + 5) * 97 + gc] = v1.y;
      dwv[(t8 + 6) * 97 + gc] = v1.z;
      dwv[(t8 + 7) * 97 + gc] = v1.w;
    }
  }
  __syncthreads();

  for (int e = tid; e < 4096; e += 256)
    smA[(e >> 6) * 65 + (e & 63)] = mlpw[e];
  if (tid < 64) {
    float ss = 0.f;
    for (int t = 0; t < 64; ++t) {
      const float v = dwv[t * 97 + tid];
      ss += v * v;
    }
    scl[tid] = 1.f / fmaxf(sqrtf(ss), 1e-12f);
  }
  __syncthreads();

  {
    const int c = tid >> 3, m = tid & 7;
    float sa[4] = {0.f, 0.f, 0.f, 0.f};
    for (int t = 0; t < 64; ++t) {
      const float qv = dwv[t * 97 + c];
#pragma unroll
      for (int j = 0; j < 4; ++j) sa[j] += qv * dwv[t * 97 + 32 + m * 4 + j];
    }
    const float qs = scl[c] * temp[head];
#pragma unroll
    for (int j = 0; j < 4; ++j) sa[j] *= qs * scl[32 + m * 4 + j];
    float mx = fmaxf(fmaxf(sa[0], sa[1]), fmaxf(sa[2], sa[3]));
    for (int off = 1; off < 8; off <<= 1) mx = fmaxf(mx, __shfl_xor(mx, off, 8));
    float sum = 0.f;
#pragma unroll
    for (int j = 0; j < 4; ++j) {
      sa[j] = expf(sa[j] - mx);
      sum += sa[j];
    }
    for (int off = 1; off < 8; off <<= 1) sum += __shfl_xor(sum, off, 8);
    const float inv = 1.f / sum;
#pragma unroll
    for (int j = 0; j < 4; ++j) attnS[c * 33 + m * 4 + j] = sa[j] * inv;
  }
  __syncthreads();

  {
    const int c = ch;
    float ov[8] = {0.f, 0.f, 0.f, 0.f, 0.f, 0.f, 0.f, 0.f};
    const int tb = iy * 8 * 97 + 64;
    for (int d = 0; d < 32; ++d) {
      const float a = attnS[c * 33 + d];
#pragma unroll
      for (int j = 0; j < 8; ++j) ov[j] += a * dwv[tb + j * 97 + d];
    }
    float gt[8];
#pragma unroll
    for (int j = 0; j < 8; ++j) gt[j] = mlpb[iy * 8 + j];
    for (int x = 0; x < 64; ++x) {
      const float vv = dwv[x * 97 + 64 + c];
#pragma unroll
      for (int j = 0; j < 8; ++j) gt[j] += vv * smA[(iy * 8 + j) * 65 + x];
    }
    float res[8];
#pragma unroll
    for (int j = 0; j < 8; ++j) {
      const float gg = gt[j];
      res[j] = ov[j] * (0.5f * gg * (1.f + erff(gg * 0.70710678118654752f)));
    }
    float* dst = yw + (((size_t)(b * 1024 + win) * 192 + head * 32 + c) * 64
                       + iy * 8);
    *(float4*)dst       = make_float4(res[0], res[1], res[2], res[3]);
    *(float4*)(dst + 4) = make_float4(res[4], res[5], res[6], res[7]);
  }
}

// ---------------------------------------------------------------------------
// K3: proj GEMM reading windowed yw, writing spatial out (+bias).
// ---------------------------------------------------------------------------
__global__ __launch_bounds__(256) void proj_gemm(
    const float* __restrict__ yw, const float* __restrict__ Wm,
    const float* __restrict__ bias, float* __restrict__ out) {
  __shared__ float As[16][68];
  __shared__ float Bs[16][256];
  const int ptile = blockIdx.x;
  const int ot = blockIdx.y * 64;
  const int b  = blockIdx.z;
  const int h1 = ptile >> 3, w4 = ptile & 7;
  const int win0 = h1 * 32 + w4 * 4;
  const int tid = threadIdx.x;
  const int tx = tid & 15, ty = tid >> 4;
  const int oA = tid >> 2, kA = (tid & 3) * 4;
  float acc[4][16];
#pragma unroll
  for (int i = 0; i < 4; ++i)
#pragma unroll
    for (int j = 0; j < 16; ++j) acc[i][j] = 0.f;

  const float* ywb = yw + (size_t)(b * 1024 + win0) * 192 * 64;
  for (int k0 = 0; k0 < 192; k0 += 16) {
    float4 av = *(const float4*)(Wm + (size_t)(ot + oA) * 192 + k0 + kA);
    As[kA + 0][oA] = av.x;
    As[kA + 1][oA] = av.y;
    As[kA + 2][oA] = av.z;
    As[kA + 3][oA] = av.w;
#pragma unroll
    for (int i = 0; i < 4; ++i) {
      const int f4 = tid + 256 * i;
      const int k = f4 >> 6, p4 = f4 & 63;
      const int wv = p4 >> 4, tt = (p4 & 15) * 4;
      *(float4*)&Bs[k][p4 * 4] =
          *(const float4*)(ywb + ((size_t)wv * 192 + k0 + k) * 64 + tt);
    }
    __syncthreads();
#pragma unroll
    for (int k = 0; k < 16; ++k) {
      const float a0 = As[k][ty * 4 + 0];
      const float a1 = As[k][ty * 4 + 1];
      const float a2 = As[k][ty * 4 + 2];
      const float a3 = As[k][ty * 4 + 3];
#pragma unroll
      for (int j = 0; j < 16; ++j) {
        const float bv = Bs[k][tx + 16 * j];
        acc[0][j] += a0 * bv;
        acc[1][j] += a1 * bv;
        acc[2][j] += a2 * bv;
        acc[3][j] += a3 * bv;
      }
    }
    __syncthreads();
  }
  const int colbase = w4 * 32;
#pragma unroll
  for (int i = 0; i < 4; ++i) {
    const int o = ot + ty * 4 + i;
    const float bv = bias[o];
    float* ob = out + ((size_t)(b * 192 + o) * 256 + h1 * 8) * 256 + colbase;
#pragma unroll
    for (int j = 0; j < 16; ++j) {
      const int p = tx + 16 * j;
      const int wv = p >> 6;
      const int t = p & 63;
      ob[(t >> 3) * 256 + wv * 8 + (t & 7)] = acc[i][j] + bv;
    }
  }
}

extern "C" void kernel_launch(void* const* d_in, const int* in_sizes, int n_in,
                              void* d_out, int out_size, void* d_ws, size_t ws_size,
                              hipStream_t stream) {
  const float* x           = (const float*)d_in[0];
  const float* w_qkv       = (const float*)d_in[1];
  const float* w_dw        = (const float*)d_in[2];
  const float* temperature = (const float*)d_in[3];
  const float* mlp_w       = (const float*)d_in[4];
  const float* mlp_b       = (const float*)d_in[5];
  const float* proj_w      = (const float*)d_in[6];
  const float* proj_b      = (const float*)d_in[7];
  float* out = (float*)d_out;

  // Workspace (402.65 MB, verified footprint):
  //   [0 .. 25165824)         slice: spatial conv1x1 output for one 192-ch
  //                           group; reused as yw after dwconv staging.
  //   [25165824 .. 100663296) Bw: windowed dw-qkv, all 576 channels.
  float* slice = (float*)d_ws;
  float* Bw    = slice + (size_t)2 * 192 * HWSZ;   // +25165824

  for (int g = 0; g < 3; ++g) {
    conv1x1_gemm<<<dim3(1024, 3, 2), 256, 0, stream>>>(
        x, w_qkv + (size_t)g * 192 * CIN, slice);
    dwconv_win<<<dim3(192, 32, 2), 256, 0, stream>>>(
        slice, w_dw, Bw, g * 192);
  }
  attn_bw<<<dim3(12288), 256, 0, stream>>>(Bw, temperature, mlp_w, mlp_b,
                                           slice);
  proj_gemm<<<dim3(256, 3, 2), 256, 0, stream>>>(slice, proj_w, proj_b, out);
}

// Round 4
// 1020.395 us; speedup vs baseline: 5.5192x; 1.7130x over previous
//
#include <hip/hip_runtime.h>
#include <math.h>

#define CIN   192
#define C3    576
#define HWSZ  65536   // 256*256

// ---------------------------------------------------------------------------
// K1: fp32 tiled GEMM for qkv 1x1 conv (spatial output, one 192-ch group).
// Mout derived from gridDim.y (grid.y=3 -> 192 output channels).
// ---------------------------------------------------------------------------
__global__ __launch_bounds__(256) void conv1x1_gemm(
    const float* __restrict__ X, const float* __restrict__ Wm,
    float* __restrict__ Y) {
  __shared__ float As[16][68];
  __shared__ float Bs[16][68];
  const int pt = blockIdx.x * 64;
  const int ot = blockIdx.y * 64;
  const int b  = blockIdx.z;
  const int Mout = gridDim.y * 64;
  const float* Xb = X + (size_t)b * CIN * HWSZ;
  float* Yb = Y + (size_t)b * (size_t)Mout * HWSZ;
  const int tid = threadIdx.x;
  const int tx = tid & 15, ty = tid >> 4;
  const int oA = tid >> 2;
  const int kA = (tid & 3) * 4;
  const int kB = tid >> 4;
  const int pB = (tid & 15) * 4;
  float acc[4][4];
#pragma unroll
  for (int i = 0; i < 4; ++i)
#pragma unroll
    for (int j = 0; j < 4; ++j) acc[i][j] = 0.f;

  for (int k0 = 0; k0 < CIN; k0 += 16) {
    float4 av = *(const float4*)(Wm + (size_t)(ot + oA) * CIN + k0 + kA);
    As[kA + 0][oA] = av.x;
    As[kA + 1][oA] = av.y;
    As[kA + 2][oA] = av.z;
    As[kA + 3][oA] = av.w;
    *(float4*)&Bs[kB][pB] =
        *(const float4*)(Xb + (size_t)(k0 + kB) * HWSZ + pt + pB);
    __syncthreads();
#pragma unroll
    for (int k = 0; k < 16; ++k) {
      const float4 a4 = *(const float4*)&As[k][ty * 4];
      const float4 b4 = *(const float4*)&Bs[k][tx * 4];
      const float avr[4] = {a4.x, a4.y, a4.z, a4.w};
      const float bvr[4] = {b4.x, b4.y, b4.z, b4.w};
#pragma unroll
      for (int i = 0; i < 4; ++i)
#pragma unroll
        for (int j = 0; j < 4; ++j) acc[i][j] += avr[i] * bvr[j];
    }
    __syncthreads();
  }
#pragma unroll
  for (int i = 0; i < 4; ++i) {
    const int o = ot + ty * 4 + i;
    float4 r;
    r.x = acc[i][0]; r.y = acc[i][1]; r.z = acc[i][2]; r.w = acc[i][3];
    *(float4*)(Yb + (size_t)o * HWSZ + pt + tx * 4) = r;
  }
}

// ---------------------------------------------------------------------------
// K2a: depthwise 3x3 conv for one 192-channel group (slice layout
// [b][192][HWSZ]). Writes windowed layout:
// Bw[((b*1024+win)*576 + gbase+gc)*64 + t].  (Verified: ~38 us/launch.)
// ---------------------------------------------------------------------------
__global__ __launch_bounds__(256) void dwconv_win(
    const float* __restrict__ qkv, const float* __restrict__ wdw,
    float* __restrict__ Bw, int gbase) {
  __shared__ float t[10][264];
  const int gc = blockIdx.x;     // 0..191 within slice
  const int h1 = blockIdx.y;     // 0..31
  const int b  = blockIdx.z;
  const int tid = threadIdx.x;
  const int r0 = h1 * 8 - 1;
  const float* src = qkv + ((size_t)b * 192 + gc) * HWSZ;

  for (int idx = tid; idx < 640; idx += 256) {
    const int row = idx >> 6, cv = idx & 63;
    const int gr = r0 + row;
    float4 v = make_float4(0.f, 0.f, 0.f, 0.f);
    if ((unsigned)gr < 256u) v = *(const float4*)(src + gr * 256 + cv * 4);
    *(float4*)&t[row][4 + cv * 4] = v;
  }
  if (tid < 10) { t[tid][3] = 0.f; t[tid][260] = 0.f; }
  __syncthreads();

  const float* w9 = wdw + (size_t)(gbase + gc) * 9;
  const float w0 = w9[0], w1 = w9[1], w2 = w9[2];
  const float w3 = w9[3], w4 = w9[4], w5 = w9[5];
  const float w6 = w9[6], w7 = w9[7], w8 = w9[8];

  const int c = tid;                  // spatial col 0..255
  const int wv = c >> 3, tt = c & 7;  // window-in-row, token-col
  float* rec = Bw + (((size_t)(b * 1024 + h1 * 32 + wv) * C3) + gbase + gc) * 64
               + tt;

  float x0 = t[0][c + 3], x1 = t[0][c + 4], x2 = t[0][c + 5];
  float y0 = t[1][c + 3], y1 = t[1][c + 4], y2 = t[1][c + 5];
#pragma unroll
  for (int rr = 1; rr <= 8; ++rr) {
    const float z0 = t[rr + 1][c + 3], z1 = t[rr + 1][c + 4],
                z2 = t[rr + 1][c + 5];
    const float res = x0 * w0 + x1 * w1 + x2 * w2
                    + y0 * w3 + y1 * w4 + y2 * w5
                    + z0 * w6 + z1 * w7 + z2 * w8;
    rec[(rr - 1) * 8] = res;
    x0 = y0; x1 = y1; x2 = y2;
    y0 = z0; y1 = z1; y2 = z2;
  }
}

// ---------------------------------------------------------------------------
// K2b: gate GEMM: gate[row][y] = GELU( sum_x V[row][x]*mlpw[y][x] + mlpb[y] )
// for all 393216 V rows (channels 384..575 of each win record in Bw).
// Writes GELU'd gate DIRECTLY into the yw buffer at the addresses attn_bw2
// will later read-multiply-overwrite (same [rec*192+ch]*64+t layout).
// Structure cloned from the proven conv1x1_gemm inner loop (transposed LDS
// tiles, float4 reads, 4x4 accumulators).
// ---------------------------------------------------------------------------
__global__ __launch_bounds__(256) void gate_gemm(
    const float* __restrict__ Bw, const float* __restrict__ mlpw,
    const float* __restrict__ mlpb, float* __restrict__ gate) {
  __shared__ float VT[64 * 68];   // [x][row]
  __shared__ float WT[64 * 68];   // [x][y]
  const int blk = blockIdx.x;
  const int rec = blk / 3;        // b*1024+win  (0..2047)
  const int sub = blk - rec * 3;  // 64-row chunk within the 192 V rows
  const int tid = threadIdx.x;

  const float* vsrc = Bw + (size_t)rec * (C3 * 64) + (384 + sub * 64) * 64;
#pragma unroll
  for (int i = 0; i < 4; ++i) {
    const int f4 = tid + 256 * i;
    const int r = f4 >> 4, x0 = (f4 & 15) * 4;
    const float4 v = *(const float4*)(vsrc + r * 64 + x0);
    VT[(x0 + 0) * 68 + r] = v.x;
    VT[(x0 + 1) * 68 + r] = v.y;
    VT[(x0 + 2) * 68 + r] = v.z;
    VT[(x0 + 3) * 68 + r] = v.w;
    const float4 w = *(const float4*)(mlpw + r * 64 + x0);
    WT[(x0 + 0) * 68 + r] = w.x;
    WT[(x0 + 1) * 68 + r] = w.y;
    WT[(x0 + 2) * 68 + r] = w.z;
    WT[(x0 + 3) * 68 + r] = w.w;
  }
  __syncthreads();

  const int tx = tid & 15, ty = tid >> 4;
  float acc[4][4];
#pragma unroll
  for (int i = 0; i < 4; ++i)
#pragma unroll
    for (int j = 0; j < 4; ++j) acc[i][j] = 0.f;

  for (int x = 0; x < 64; ++x) {
    const float4 a4 = *(const float4*)&VT[x * 68 + ty * 4];
    const float4 b4 = *(const float4*)&WT[x * 68 + tx * 4];
    const float avr[4] = {a4.x, a4.y, a4.z, a4.w};
    const float bvr[4] = {b4.x, b4.y, b4.z, b4.w};
#pragma unroll
    for (int i = 0; i < 4; ++i)
#pragma unroll
      for (int j = 0; j < 4; ++j) acc[i][j] += avr[i] * bvr[j];
  }

  const float kE = 0.70710678118654752f;
  const float b0 = mlpb[tx * 4 + 0], b1 = mlpb[tx * 4 + 1];
  const float b2 = mlpb[tx * 4 + 2], b3 = mlpb[tx * 4 + 3];
#pragma unroll
  for (int i = 0; i < 4; ++i) {
    const int row = ty * 4 + i;   // V-channel within this 64-chunk
    float g0 = acc[i][0] + b0;
    float g1 = acc[i][1] + b1;
    float g2 = acc[i][2] + b2;
    float g3 = acc[i][3] + b3;
    g0 = 0.5f * g0 * (1.f + erff(g0 * kE));
    g1 = 0.5f * g1 * (1.f + erff(g1 * kE));
    g2 = 0.5f * g2 * (1.f + erff(g2 * kE));
    g3 = 0.5f * g3 * (1.f + erff(g3 * kE));
    float* dst = gate + ((size_t)rec * 192 + sub * 64 + row) * 64 + tx * 4;
    *(float4*)dst = make_float4(g0, g1, g2, g3);
  }
}

// ---------------------------------------------------------------------------
// K2c: windowed channel attention (gate precomputed).
// Compute phases VERBATIM from the harness-verified R0/R3 structure
// (token-major dwv stride 97, scalar LDS reads). smA / gate loop removed:
// LDS 29.3 KB -> 5 blocks/CU. Gate is read from yw (written by gate_gemm),
// multiplied, and the result overwrites the same addresses.
// ---------------------------------------------------------------------------
__global__ __launch_bounds__(256, 5) void attn_bw2(
    const float* __restrict__ Bw, const float* __restrict__ temp,
    float* __restrict__ yw) {
  __shared__ float dwv[64 * 97];
  __shared__ float attnS[32 * 33];
  __shared__ float scl[64];
  const int bid = blockIdx.x;
  const int b   = bid / 6144;
  const int rr  = bid % 6144;
  const int xcd = rr & 7;
  const int s   = rr >> 3;
  const int head = s % 6;
  const int wloc = s / 6;
  const int win  = xcd * 128 + wloc;
  const int tid = threadIdx.x;
  const int ch = tid >> 3;   // 0..31
  const int iy = tid & 7;    // 0..7

  // ---- staging: windowed Bw -> token-major dwv [t*97 + gc] ----
  {
    const float* rec = Bw + (size_t)(b * 1024 + win) * C3 * 64;
    const int t8 = iy * 8;
#pragma unroll
    for (int g = 0; g < 3; ++g) {
      const float* sp = rec + (size_t)(g * 192 + head * 32 + ch) * 64 + t8;
      const float4 v0 = *(const float4*)sp;
      const float4 v1 = *(const float4*)(sp + 4);
      const int gc = g * 32 + ch;
      dwv[(t8 + 0) * 97 + gc] = v0.x;
      dwv[(t8 + 1) * 97 + gc] = v0.y;
      dwv[(t8 + 2) * 97 + gc] = v0.z;
      dwv[(t8 + 3) * 97 + gc] = v0.w;
      dwv[(t8 + 4) * 97 + gc] = v1.x;
      dwv[(t8 + 5) * 97 + gc] = v1.y;
      dwv[(t8 + 6) * 97 + gc] = v1.z;
      dwv[(t8 + 7) * 97 + gc] = v1.w;
    }
  }
  __syncthreads();

  if (tid < 64) {
    float ss = 0.f;
    for (int t = 0; t < 64; ++t) {
      const float v = dwv[t * 97 + tid];
      ss += v * v;
    }
    scl[tid] = 1.f / fmaxf(sqrtf(ss), 1e-12f);
  }
  __syncthreads();

  {
    const int c = tid >> 3, m = tid & 7;
    float sa[4] = {0.f, 0.f, 0.f, 0.f};
    for (int t = 0; t < 64; ++t) {
      const float qv = dwv[t * 97 + c];
#pragma unroll
      for (int j = 0; j < 4; ++j) sa[j] += qv * dwv[t * 97 + 32 + m * 4 + j];
    }
    const float qs = scl[c] * temp[head];
#pragma unroll
    for (int j = 0; j < 4; ++j) sa[j] *= qs * scl[32 + m * 4 + j];
    float mx = fmaxf(fmaxf(sa[0], sa[1]), fmaxf(sa[2], sa[3]));
    for (int off = 1; off < 8; off <<= 1) mx = fmaxf(mx, __shfl_xor(mx, off, 8));
    float sum = 0.f;
#pragma unroll
    for (int j = 0; j < 4; ++j) {
      sa[j] = expf(sa[j] - mx);
      sum += sa[j];
    }
    for (int off = 1; off < 8; off <<= 1) sum += __shfl_xor(sum, off, 8);
    const float inv = 1.f / sum;
#pragma unroll
    for (int j = 0; j < 4; ++j) attnS[c * 33 + m * 4 + j] = sa[j] * inv;
  }
  __syncthreads();

  {
    const int c = ch;
    float* dst = yw + (((size_t)(b * 1024 + win) * 192 + head * 32 + c) * 64
                       + iy * 8);
    // issue gate read early to hide latency under the AV loop
    const float4 gA = *(const float4*)dst;
    const float4 gB = *(const float4*)(dst + 4);
    float ov[8] = {0.f, 0.f, 0.f, 0.f, 0.f, 0.f, 0.f, 0.f};
    const int tb = iy * 8 * 97 + 64;
    for (int d = 0; d < 32; ++d) {
      const float a = attnS[c * 33 + d];
#pragma unroll
      for (int j = 0; j < 8; ++j) ov[j] += a * dwv[tb + j * 97 + d];
    }
    *(float4*)dst       = make_float4(ov[0] * gA.x, ov[1] * gA.y,
                                      ov[2] * gA.z, ov[3] * gA.w);
    *(float4*)(dst + 4) = make_float4(ov[4] * gB.x, ov[5] * gB.y,
                                      ov[6] * gB.z, ov[7] * gB.w);
  }
}

// ---------------------------------------------------------------------------
// K3: proj GEMM reading windowed yw, writing spatial out (+bias).
// ---------------------------------------------------------------------------
__global__ __launch_bounds__(256) void proj_gemm(
    const float* __restrict__ yw, const float* __restrict__ Wm,
    const float* __restrict__ bias, float* __restrict__ out) {
  __shared__ float As[16][68];
  __shared__ float Bs[16][256];
  const int ptile = blockIdx.x;
  const int ot = blockIdx.y * 64;
  const int b  = blockIdx.z;
  const int h1 = ptile >> 3, w4 = ptile & 7;
  const int win0 = h1 * 32 + w4 * 4;
  const int tid = threadIdx.x;
  const int tx = tid & 15, ty = tid >> 4;
  const int oA = tid >> 2, kA = (tid & 3) * 4;
  float acc[4][16];
#pragma unroll
  for (int i = 0; i < 4; ++i)
#pragma unroll
    for (int j = 0; j < 16; ++j) acc[i][j] = 0.f;

  const float* ywb = yw + (size_t)(b * 1024 + win0) * 192 * 64;
  for (int k0 = 0; k0 < 192; k0 += 16) {
    float4 av = *(const float4*)(Wm + (size_t)(ot + oA) * 192 + k0 + kA);
    As[kA + 0][oA] = av.x;
    As[kA + 1][oA] = av.y;
    As[kA + 2][oA] = av.z;
    As[kA + 3][oA] = av.w;
#pragma unroll
    for (int i = 0; i < 4; ++i) {
      const int f4 = tid + 256 * i;
      const int k = f4 >> 6, p4 = f4 & 63;
      const int wv = p4 >> 4, tt = (p4 & 15) * 4;
      *(float4*)&Bs[k][p4 * 4] =
          *(const float4*)(ywb + ((size_t)wv * 192 + k0 + k) * 64 + tt);
    }
    __syncthreads();
#pragma unroll
    for (int k = 0; k < 16; ++k) {
      const float a0 = As[k][ty * 4 + 0];
      const float a1 = As[k][ty * 4 + 1];
      const float a2 = As[k][ty * 4 + 2];
      const float a3 = As[k][ty * 4 + 3];
#pragma unroll
      for (int j = 0; j < 16; ++j) {
        const float bv = Bs[k][tx + 16 * j];
        acc[0][j] += a0 * bv;
        acc[1][j] += a1 * bv;
        acc[2][j] += a2 * bv;
        acc[3][j] += a3 * bv;
      }
    }
    __syncthreads();
  }
  const int colbase = w4 * 32;
#pragma unroll
  for (int i = 0; i < 4; ++i) {
    const int o = ot + ty * 4 + i;
    const float bv = bias[o];
    float* ob = out + ((size_t)(b * 192 + o) * 256 + h1 * 8) * 256 + colbase;
#pragma unroll
    for (int j = 0; j < 16; ++j) {
      const int p = tx + 16 * j;
      const int wv = p >> 6;
      const int t = p & 63;
      ob[(t >> 3) * 256 + wv * 8 + (t & 7)] = acc[i][j] + bv;
    }
  }
}

extern "C" void kernel_launch(void* const* d_in, const int* in_sizes, int n_in,
                              void* d_out, int out_size, void* d_ws, size_t ws_size,
                              hipStream_t stream) {
  const float* x           = (const float*)d_in[0];
  const float* w_qkv       = (const float*)d_in[1];
  const float* w_dw        = (const float*)d_in[2];
  const float* temperature = (const float*)d_in[3];
  const float* mlp_w       = (const float*)d_in[4];
  const float* mlp_b       = (const float*)d_in[5];
  const float* proj_w      = (const float*)d_in[6];
  const float* proj_b      = (const float*)d_in[7];
  float* out = (float*)d_out;

  // Workspace (402.65 MB, verified footprint):
  //   [0 .. 25165824)         slice: spatial conv1x1 output for one 192-ch
  //                           group; reused as gate/yw buffer afterwards.
  //   [25165824 .. 100663296) Bw: windowed dw-qkv, all 576 channels.
  float* slice = (float*)d_ws;
  float* Bw    = slice + (size_t)2 * 192 * HWSZ;   // +25165824

  for (int g = 0; g < 3; ++g) {
    conv1x1_gemm<<<dim3(1024, 3, 2), 256, 0, stream>>>(
        x, w_qkv + (size_t)g * 192 * CIN, slice);
    dwconv_win<<<dim3(192, 32, 2), 256, 0, stream>>>(
        slice, w_dw, Bw, g * 192);
  }
  // gate = GELU(V @ mlp^T + b) written into the yw buffer (slice)
  gate_gemm<<<dim3(6144), 256, 0, stream>>>(Bw, mlp_w, mlp_b, slice);
  // attn reads gate from slice, multiplies, overwrites in place
  attn_bw2<<<dim3(12288), 256, 0, stream>>>(Bw, temperature, slice);
  proj_gemm<<<dim3(256, 3, 2), 256, 0, stream>>>(slice, proj_w, proj_b, out);
}

// Round 5
// 947.832 us; speedup vs baseline: 5.9417x; 1.0766x over previous
//
#include <hip/hip_runtime.h>
#include <math.h>

#define CIN   192
#define C3    576
#define HWSZ  65536   // 256*256

// ---------------------------------------------------------------------------
// K1: fp32 tiled GEMM for qkv 1x1 conv (spatial output, one 192-ch group).
// Tile 64 out x 256 pos, acc[4][16] per thread: 64 FMA vs 5 ds_read_b128
// per k (ratio 2.1 vs old 1.33). All LDS reads keep the proven 2-way-free
// tx*4 bank pattern (4 separate 64-pos blocks per thread).
// Mout derived from gridDim.y (grid.y=3 -> 192 output channels).
// ---------------------------------------------------------------------------
__global__ __launch_bounds__(256) void conv1x1_gemm(
    const float* __restrict__ X, const float* __restrict__ Wm,
    float* __restrict__ Y) {
  __shared__ float As[16][68];
  __shared__ float Bs[16][256];
  const int pt = blockIdx.x * 256;
  const int ot = blockIdx.y * 64;
  const int b  = blockIdx.z;
  const int Mout = gridDim.y * 64;
  const float* Xb = X + (size_t)b * CIN * HWSZ;
  float* Yb = Y + (size_t)b * (size_t)Mout * HWSZ;
  const int tid = threadIdx.x;
  const int tx = tid & 15, ty = tid >> 4;
  const int oA = tid >> 2;
  const int kA = (tid & 3) * 4;
  float acc[4][16];
#pragma unroll
  for (int i = 0; i < 4; ++i)
#pragma unroll
    for (int j = 0; j < 16; ++j) acc[i][j] = 0.f;

  for (int k0 = 0; k0 < CIN; k0 += 16) {
    float4 av = *(const float4*)(Wm + (size_t)(ot + oA) * CIN + k0 + kA);
    As[kA + 0][oA] = av.x;
    As[kA + 1][oA] = av.y;
    As[kA + 2][oA] = av.z;
    As[kA + 3][oA] = av.w;
#pragma unroll
    for (int i = 0; i < 4; ++i) {
      const int f4 = tid + 256 * i;
      const int k = f4 >> 6, p4 = f4 & 63;
      *(float4*)&Bs[k][p4 * 4] =
          *(const float4*)(Xb + (size_t)(k0 + k) * HWSZ + pt + p4 * 4);
    }
    __syncthreads();
#pragma unroll
    for (int k = 0; k < 16; ++k) {
      const float4 a4 = *(const float4*)&As[k][ty * 4];
      const float4 b0 = *(const float4*)&Bs[k][tx * 4];
      const float4 b1 = *(const float4*)&Bs[k][64 + tx * 4];
      const float4 b2 = *(const float4*)&Bs[k][128 + tx * 4];
      const float4 b3 = *(const float4*)&Bs[k][192 + tx * 4];
      const float avr[4] = {a4.x, a4.y, a4.z, a4.w};
      const float bvr[16] = {b0.x, b0.y, b0.z, b0.w,
                             b1.x, b1.y, b1.z, b1.w,
                             b2.x, b2.y, b2.z, b2.w,
                             b3.x, b3.y, b3.z, b3.w};
#pragma unroll
      for (int i = 0; i < 4; ++i)
#pragma unroll
        for (int j = 0; j < 16; ++j) acc[i][j] += avr[i] * bvr[j];
    }
    __syncthreads();
  }
#pragma unroll
  for (int i = 0; i < 4; ++i) {
    const int o = ot + ty * 4 + i;
#pragma unroll
    for (int j4 = 0; j4 < 4; ++j4) {
      float4 r;
      r.x = acc[i][j4 * 4 + 0];
      r.y = acc[i][j4 * 4 + 1];
      r.z = acc[i][j4 * 4 + 2];
      r.w = acc[i][j4 * 4 + 3];
      *(float4*)(Yb + (size_t)o * HWSZ + pt + j4 * 64 + tx * 4) = r;
    }
  }
}

// ---------------------------------------------------------------------------
// K2a: depthwise 3x3 conv for one 192-channel group (slice layout
// [b][192][HWSZ]). Writes windowed layout:
// Bw[((b*1024+win)*576 + gbase+gc)*64 + t].  (Verified: ~38 us/launch.)
// ---------------------------------------------------------------------------
__global__ __launch_bounds__(256) void dwconv_win(
    const float* __restrict__ qkv, const float* __restrict__ wdw,
    float* __restrict__ Bw, int gbase) {
  __shared__ float t[10][264];
  const int gc = blockIdx.x;     // 0..191 within slice
  const int h1 = blockIdx.y;     // 0..31
  const int b  = blockIdx.z;
  const int tid = threadIdx.x;
  const int r0 = h1 * 8 - 1;
  const float* src = qkv + ((size_t)b * 192 + gc) * HWSZ;

  for (int idx = tid; idx < 640; idx += 256) {
    const int row = idx >> 6, cv = idx & 63;
    const int gr = r0 + row;
    float4 v = make_float4(0.f, 0.f, 0.f, 0.f);
    if ((unsigned)gr < 256u) v = *(const float4*)(src + gr * 256 + cv * 4);
    *(float4*)&t[row][4 + cv * 4] = v;
  }
  if (tid < 10) { t[tid][3] = 0.f; t[tid][260] = 0.f; }
  __syncthreads();

  const float* w9 = wdw + (size_t)(gbase + gc) * 9;
  const float w0 = w9[0], w1 = w9[1], w2 = w9[2];
  const float w3 = w9[3], w4 = w9[4], w5 = w9[5];
  const float w6 = w9[6], w7 = w9[7], w8 = w9[8];

  const int c = tid;                  // spatial col 0..255
  const int wv = c >> 3, tt = c & 7;  // window-in-row, token-col
  float* rec = Bw + (((size_t)(b * 1024 + h1 * 32 + wv) * C3) + gbase + gc) * 64
               + tt;

  float x0 = t[0][c + 3], x1 = t[0][c + 4], x2 = t[0][c + 5];
  float y0 = t[1][c + 3], y1 = t[1][c + 4], y2 = t[1][c + 5];
#pragma unroll
  for (int rr = 1; rr <= 8; ++rr) {
    const float z0 = t[rr + 1][c + 3], z1 = t[rr + 1][c + 4],
                z2 = t[rr + 1][c + 5];
    const float res = x0 * w0 + x1 * w1 + x2 * w2
                    + y0 * w3 + y1 * w4 + y2 * w5
                    + z0 * w6 + z1 * w7 + z2 * w8;
    rec[(rr - 1) * 8] = res;
    x0 = y0; x1 = y1; x2 = y2;
    y0 = z0; y1 = z1; y2 = z2;
  }
}

// ---------------------------------------------------------------------------
// K2b: gate GEMM: gate[row][y] = GELU( sum_x V[row][x]*mlpw[y][x] + mlpb[y] )
// for all 393216 V rows (channels 384..575 of each win record in Bw).
// Writes GELU'd gate DIRECTLY into the yw buffer at the addresses attn_bw2
// will later read-multiply-overwrite (same [rec*192+ch]*64+t layout).
// ---------------------------------------------------------------------------
__global__ __launch_bounds__(256) void gate_gemm(
    const float* __restrict__ Bw, const float* __restrict__ mlpw,
    const float* __restrict__ mlpb, float* __restrict__ gate) {
  __shared__ float VT[64 * 68];   // [x][row]
  __shared__ float WT[64 * 68];   // [x][y]
  const int blk = blockIdx.x;
  const int rec = blk / 3;        // b*1024+win  (0..2047)
  const int sub = blk - rec * 3;  // 64-row chunk within the 192 V rows
  const int tid = threadIdx.x;

  const float* vsrc = Bw + (size_t)rec * (C3 * 64) + (384 + sub * 64) * 64;
#pragma unroll
  for (int i = 0; i < 4; ++i) {
    const int f4 = tid + 256 * i;
    const int r = f4 >> 4, x0 = (f4 & 15) * 4;
    const float4 v = *(const float4*)(vsrc + r * 64 + x0);
    VT[(x0 + 0) * 68 + r] = v.x;
    VT[(x0 + 1) * 68 + r] = v.y;
    VT[(x0 + 2) * 68 + r] = v.z;
    VT[(x0 + 3) * 68 + r] = v.w;
    const float4 w = *(const float4*)(mlpw + r * 64 + x0);
    WT[(x0 + 0) * 68 + r] = w.x;
    WT[(x0 + 1) * 68 + r] = w.y;
    WT[(x0 + 2) * 68 + r] = w.z;
    WT[(x0 + 3) * 68 + r] = w.w;
  }
  __syncthreads();

  const int tx = tid & 15, ty = tid >> 4;
  float acc[4][4];
#pragma unroll
  for (int i = 0; i < 4; ++i)
#pragma unroll
    for (int j = 0; j < 4; ++j) acc[i][j] = 0.f;

  for (int x = 0; x < 64; ++x) {
    const float4 a4 = *(const float4*)&VT[x * 68 + ty * 4];
    const float4 b4 = *(const float4*)&WT[x * 68 + tx * 4];
    const float avr[4] = {a4.x, a4.y, a4.z, a4.w};
    const float bvr[4] = {b4.x, b4.y, b4.z, b4.w};
#pragma unroll
    for (int i = 0; i < 4; ++i)
#pragma unroll
      for (int j = 0; j < 4; ++j) acc[i][j] += avr[i] * bvr[j];
  }

  const float kE = 0.70710678118654752f;
  const float b0 = mlpb[tx * 4 + 0], b1 = mlpb[tx * 4 + 1];
  const float b2 = mlpb[tx * 4 + 2], b3 = mlpb[tx * 4 + 3];
#pragma unroll
  for (int i = 0; i < 4; ++i) {
    const int row = ty * 4 + i;   // V-channel within this 64-chunk
    float g0 = acc[i][0] + b0;
    float g1 = acc[i][1] + b1;
    float g2 = acc[i][2] + b2;
    float g3 = acc[i][3] + b3;
    g0 = 0.5f * g0 * (1.f + erff(g0 * kE));
    g1 = 0.5f * g1 * (1.f + erff(g1 * kE));
    g2 = 0.5f * g2 * (1.f + erff(g2 * kE));
    g3 = 0.5f * g3 * (1.f + erff(g3 * kE));
    float* dst = gate + ((size_t)rec * 192 + sub * 64 + row) * 64 + tx * 4;
    *(float4*)dst = make_float4(g0, g1, g2, g3);
  }
}

// ---------------------------------------------------------------------------
// K2c: windowed channel attention (gate precomputed).
// Compute phases VERBATIM from the harness-verified R0/R3 structure
// (token-major dwv stride 97, scalar LDS reads). LDS 29.3 KB -> 5 blocks/CU.
// ---------------------------------------------------------------------------
__global__ __launch_bounds__(256, 5) void attn_bw2(
    const float* __restrict__ Bw, const float* __restrict__ temp,
    float* __restrict__ yw) {
  __shared__ float dwv[64 * 97];
  __shared__ float attnS[32 * 33];
  __shared__ float scl[64];
  const int bid = blockIdx.x;
  const int b   = bid / 6144;
  const int rr  = bid % 6144;
  const int xcd = rr & 7;
  const int s   = rr >> 3;
  const int head = s % 6;
  const int wloc = s / 6;
  const int win  = xcd * 128 + wloc;
  const int tid = threadIdx.x;
  const int ch = tid >> 3;   // 0..31
  const int iy = tid & 7;    // 0..7

  // ---- staging: windowed Bw -> token-major dwv [t*97 + gc] ----
  {
    const float* rec = Bw + (size_t)(b * 1024 + win) * C3 * 64;
    const int t8 = iy * 8;
#pragma unroll
    for (int g = 0; g < 3; ++g) {
      const float* sp = rec + (size_t)(g * 192 + head * 32 + ch) * 64 + t8;
      const float4 v0 = *(const float4*)sp;
      const float4 v1 = *(const float4*)(sp + 4);
      const int gc = g * 32 + ch;
      dwv[(t8 + 0) * 97 + gc] = v0.x;
      dwv[(t8 + 1) * 97 + gc] = v0.y;
      dwv[(t8 + 2) * 97 + gc] = v0.z;
      dwv[(t8 + 3) * 97 + gc] = v0.w;
      dwv[(t8 + 4) * 97 + gc] = v1.x;
      dwv[(t8 + 5) * 97 + gc] = v1.y;
      dwv[(t8 + 6) * 97 + gc] = v1.z;
      dwv[(t8 + 7) * 97 + gc] = v1.w;
    }
  }
  __syncthreads();

  if (tid < 64) {
    float ss = 0.f;
    for (int t = 0; t < 64; ++t) {
      const float v = dwv[t * 97 + tid];
      ss += v * v;
    }
    scl[tid] = 1.f / fmaxf(sqrtf(ss), 1e-12f);
  }
  __syncthreads();

  {
    const int c = tid >> 3, m = tid & 7;
    float sa[4] = {0.f, 0.f, 0.f, 0.f};
    for (int t = 0; t < 64; ++t) {
      const float qv = dwv[t * 97 + c];
#pragma unroll
      for (int j = 0; j < 4; ++j) sa[j] += qv * dwv[t * 97 + 32 + m * 4 + j];
    }
    const float qs = scl[c] * temp[head];
#pragma unroll
    for (int j = 0; j < 4; ++j) sa[j] *= qs * scl[32 + m * 4 + j];
    float mx = fmaxf(fmaxf(sa[0], sa[1]), fmaxf(sa[2], sa[3]));
    for (int off = 1; off < 8; off <<= 1) mx = fmaxf(mx, __shfl_xor(mx, off, 8));
    float sum = 0.f;
#pragma unroll
    for (int j = 0; j < 4; ++j) {
      sa[j] = expf(sa[j] - mx);
      sum += sa[j];
    }
    for (int off = 1; off < 8; off <<= 1) sum += __shfl_xor(sum, off, 8);
    const float inv = 1.f / sum;
#pragma unroll
    for (int j = 0; j < 4; ++j) attnS[c * 33 + m * 4 + j] = sa[j] * inv;
  }
  __syncthreads();

  {
    const int c = ch;
    float* dst = yw + (((size_t)(b * 1024 + win) * 192 + head * 32 + c) * 64
                       + iy * 8);
    // issue gate read early to hide latency under the AV loop
    const float4 gA = *(const float4*)dst;
    const float4 gB = *(const float4*)(dst + 4);
    float ov[8] = {0.f, 0.f, 0.f, 0.f, 0.f, 0.f, 0.f, 0.f};
    const int tb = iy * 8 * 97 + 64;
    for (int d = 0; d < 32; ++d) {
      const float a = attnS[c * 33 + d];
#pragma unroll
      for (int j = 0; j < 8; ++j) ov[j] += a * dwv[tb + j * 97 + d];
    }
    *(float4*)dst       = make_float4(ov[0] * gA.x, ov[1] * gA.y,
                                      ov[2] * gA.z, ov[3] * gA.w);
    *(float4*)(dst + 4) = make_float4(ov[4] * gB.x, ov[5] * gB.y,
                                      ov[6] * gB.z, ov[7] * gB.w);
  }
}

// ---------------------------------------------------------------------------
// K3: proj GEMM reading windowed yw, writing spatial out (+bias).
// Inner loop vectorized: 4x float4 Bs reads (2-way-free tx*4 pattern, B
// staging layout unchanged) + float4 A read; 64 FMA vs 5 ds_read_b128 per k.
// ---------------------------------------------------------------------------
__global__ __launch_bounds__(256) void proj_gemm(
    const float* __restrict__ yw, const float* __restrict__ Wm,
    const float* __restrict__ bias, float* __restrict__ out) {
  __shared__ float As[16][68];
  __shared__ float Bs[16][256];
  const int ptile = blockIdx.x;
  const int ot = blockIdx.y * 64;
  const int b  = blockIdx.z;
  const int h1 = ptile >> 3, w4 = ptile & 7;
  const int win0 = h1 * 32 + w4 * 4;
  const int tid = threadIdx.x;
  const int tx = tid & 15, ty = tid >> 4;
  const int oA = tid >> 2, kA = (tid & 3) * 4;
  float acc[4][16];
#pragma unroll
  for (int i = 0; i < 4; ++i)
#pragma unroll
    for (int j = 0; j < 16; ++j) acc[i][j] = 0.f;

  const float* ywb = yw + (size_t)(b * 1024 + win0) * 192 * 64;
  for (int k0 = 0; k0 < 192; k0 += 16) {
    float4 av = *(const float4*)(Wm + (size_t)(ot + oA) * 192 + k0 + kA);
    As[kA + 0][oA] = av.x;
    As[kA + 1][oA] = av.y;
    As[kA + 2][oA] = av.z;
    As[kA + 3][oA] = av.w;
#pragma unroll
    for (int i = 0; i < 4; ++i) {
      const int f4 = tid + 256 * i;
      const int k = f4 >> 6, p4 = f4 & 63;
      const int wv = p4 >> 4, tt = (p4 & 15) * 4;
      *(float4*)&Bs[k][p4 * 4] =
          *(const float4*)(ywb + ((size_t)wv * 192 + k0 + k) * 64 + tt);
    }
    __syncthreads();
#pragma unroll
    for (int k = 0; k < 16; ++k) {
      const float4 a4 = *(const float4*)&As[k][ty * 4];
      const float4 b0 = *(const float4*)&Bs[k][tx * 4];
      const float4 b1 = *(const float4*)&Bs[k][64 + tx * 4];
      const float4 b2 = *(const float4*)&Bs[k][128 + tx * 4];
      const float4 b3 = *(const float4*)&Bs[k][192 + tx * 4];
      const float avr[4] = {a4.x, a4.y, a4.z, a4.w};
      const float bvr[16] = {b0.x, b0.y, b0.z, b0.w,
                             b1.x, b1.y, b1.z, b1.w,
                             b2.x, b2.y, b2.z, b2.w,
                             b3.x, b3.y, b3.z, b3.w};
#pragma unroll
      for (int i = 0; i < 4; ++i)
#pragma unroll
        for (int j = 0; j < 16; ++j) acc[i][j] += avr[i] * bvr[j];
    }
    __syncthreads();
  }
  const int colbase = w4 * 32;
#pragma unroll
  for (int i = 0; i < 4; ++i) {
    const int o = ot + ty * 4 + i;
    const float bv = bias[o];
    float* ob = out + ((size_t)(b * 192 + o) * 256 + h1 * 8) * 256 + colbase;
#pragma unroll
    for (int j = 0; j < 16; ++j) {
      const int p = (j >> 2) * 64 + tx * 4 + (j & 3);
      const int wv = p >> 6;
      const int t = p & 63;
      ob[(t >> 3) * 256 + wv * 8 + (t & 7)] = acc[i][j] + bv;
    }
  }
}

extern "C" void kernel_launch(void* const* d_in, const int* in_sizes, int n_in,
                              void* d_out, int out_size, void* d_ws, size_t ws_size,
                              hipStream_t stream) {
  const float* x           = (const float*)d_in[0];
  const float* w_qkv       = (const float*)d_in[1];
  const float* w_dw        = (const float*)d_in[2];
  const float* temperature = (const float*)d_in[3];
  const float* mlp_w       = (const float*)d_in[4];
  const float* mlp_b       = (const float*)d_in[5];
  const float* proj_w      = (const float*)d_in[6];
  const float* proj_b      = (const float*)d_in[7];
  float* out = (float*)d_out;

  // Workspace (402.65 MB, verified footprint):
  //   [0 .. 25165824)         slice: spatial conv1x1 output for one 192-ch
  //                           group; reused as gate/yw buffer afterwards.
  //   [25165824 .. 100663296) Bw: windowed dw-qkv, all 576 channels.
  float* slice = (float*)d_ws;
  float* Bw    = slice + (size_t)2 * 192 * HWSZ;   // +25165824

  for (int g = 0; g < 3; ++g) {
    conv1x1_gemm<<<dim3(256, 3, 2), 256, 0, stream>>>(
        x, w_qkv + (size_t)g * 192 * CIN, slice);
    dwconv_win<<<dim3(192, 32, 2), 256, 0, stream>>>(
        slice, w_dw, Bw, g * 192);
  }
  // gate = GELU(V @ mlp^T + b) written into the yw buffer (slice)
  gate_gemm<<<dim3(6144), 256, 0, stream>>>(Bw, mlp_w, mlp_b, slice);
  // attn reads gate from slice, multiplies, overwrites in place
  attn_bw2<<<dim3(12288), 256, 0, stream>>>(Bw, temperature, slice);
  proj_gemm<<<dim3(256, 3, 2), 256, 0, stream>>>(slice, proj_w, proj_b, out);
}

// Round 6
// 803.571 us; speedup vs baseline: 7.0084x; 1.1795x over previous
//
#include <hip/hip_runtime.h>
#include <math.h>

#define CIN   192
#define C3    576
#define HWSZ  65536   // 256*256

typedef __attribute__((ext_vector_type(8))) short bf16x8;
typedef __attribute__((ext_vector_type(4))) float f32x4;

// fp32 -> (hi, lo) bf16 pair, RNE. x ≈ hi + lo with ~2^-17 relative error.
__device__ inline void cvt_hilo(float x, short& hi, short& lo) {
  union { float f; unsigned u; } a; a.f = x;
  unsigned hb = (a.u + 0x7FFFu + ((a.u >> 16) & 1u)) & 0xFFFF0000u;
  hi = (short)(hb >> 16);
  union { unsigned u; float f; } h; h.u = hb;
  float r = x - h.f;
  union { float f; unsigned u; } c; c.f = r;
  lo = (short)((c.u + 0x7FFFu + ((c.u >> 16) & 1u)) >> 16);
}

// ---------------------------------------------------------------------------
// K1: qkv 1x1 conv as split-bf16 MFMA GEMM (one 192-ch out group / launch).
// Y[o][p] = sum_k W[o][k] X[k][p].  W,X split hi+lo bf16; 3 MFMA products
// (hh, hl, lh) accumulate in fp32 -> ~1e-5 relative error.
// Block: 64 out x 256 pos, 4 waves; wave w owns pos-tiles w*4..w*4+3 and all
// 4 out-tiles (acc[4][4] f32x4). LDS holds frag-packed A/B (lane*16B linear,
// conflict-free b128 reads/writes). mfma_f32_16x16x32_bf16 lane layout:
// A[m][k]: m=l&15, k=(l>>4)*8+j ; B[k][n]: n=l&15, k=(l>>4)*8+j ;
// D[m][n]: n=l&15, m=(l>>4)*4+reg.
// ---------------------------------------------------------------------------
__global__ __launch_bounds__(256) void conv1x1_mfma(
    const float* __restrict__ X, const float* __restrict__ Wm,
    float* __restrict__ Y) {
  __shared__ short Ah[4][64][8];    // [out-tile][lane][j]
  __shared__ short Al[4][64][8];
  __shared__ short Bh[16][64][8];   // [pos-tile][lane][j]
  __shared__ short Bl[16][64][8];
  const int pt = blockIdx.x * 256;
  const int ot = blockIdx.y * 64;
  const int b  = blockIdx.z;
  const int Mout = gridDim.y * 64;
  const float* Xb = X + (size_t)b * CIN * HWSZ;
  float* Yb = Y + (size_t)b * (size_t)Mout * HWSZ;
  const int tid = threadIdx.x;
  const int lane = tid & 63;
  const int wave = tid >> 6;

  f32x4 acc[4][4];
#pragma unroll
  for (int j = 0; j < 4; ++j)
#pragma unroll
    for (int m = 0; m < 4; ++m) acc[j][m] = (f32x4){0.f, 0.f, 0.f, 0.f};

  for (int k0 = 0; k0 < CIN; k0 += 32) {
    __syncthreads();
    // ---- stage A (weights): one frag-lane per thread ----
    {
      const int wt = tid >> 6, l = tid & 63;
      const int o = ot + wt * 16 + (l & 15);
      const int kk = k0 + (l >> 4) * 8;
      const float4 w0 = *(const float4*)(Wm + (size_t)o * CIN + kk);
      const float4 w1 = *(const float4*)(Wm + (size_t)o * CIN + kk + 4);
      const float wv[8] = {w0.x, w0.y, w0.z, w0.w, w1.x, w1.y, w1.z, w1.w};
      short hv[8], lv[8];
#pragma unroll
      for (int j = 0; j < 8; ++j) cvt_hilo(wv[j], hv[j], lv[j]);
      *(bf16x8*)(&Ah[wt][l][0]) =
          (bf16x8){hv[0], hv[1], hv[2], hv[3], hv[4], hv[5], hv[6], hv[7]};
      *(bf16x8*)(&Al[wt][l][0]) =
          (bf16x8){lv[0], lv[1], lv[2], lv[3], lv[4], lv[5], lv[6], lv[7]};
    }
    // ---- stage B (x): 4 frag-lanes per thread ----
#pragma unroll
    for (int q = 0; q < 4; ++q) {
      const int flg = q * 256 + tid;
      const int n = flg >> 6, l = flg & 63;
      const int p = pt + n * 16 + (l & 15);
      const int kk = k0 + (l >> 4) * 8;
      float xv[8];
#pragma unroll
      for (int j = 0; j < 8; ++j) xv[j] = Xb[(size_t)(kk + j) * HWSZ + p];
      short hv[8], lv[8];
#pragma unroll
      for (int j = 0; j < 8; ++j) cvt_hilo(xv[j], hv[j], lv[j]);
      *(bf16x8*)(&Bh[n][l][0]) =
          (bf16x8){hv[0], hv[1], hv[2], hv[3], hv[4], hv[5], hv[6], hv[7]};
      *(bf16x8*)(&Bl[n][l][0]) =
          (bf16x8){lv[0], lv[1], lv[2], lv[3], lv[4], lv[5], lv[6], lv[7]};
    }
    __syncthreads();

    // ---- MFMA: wave computes out-tiles 0..3 x its 4 pos-tiles ----
    bf16x8 bh[4], bl[4];
#pragma unroll
    for (int m = 0; m < 4; ++m) {
      bh[m] = *(const bf16x8*)(&Bh[wave * 4 + m][lane][0]);
      bl[m] = *(const bf16x8*)(&Bl[wave * 4 + m][lane][0]);
    }
#pragma unroll
    for (int j = 0; j < 4; ++j) {
      const bf16x8 ah = *(const bf16x8*)(&Ah[j][lane][0]);
      const bf16x8 al = *(const bf16x8*)(&Al[j][lane][0]);
#pragma unroll
      for (int m = 0; m < 4; ++m) {
        acc[j][m] = __builtin_amdgcn_mfma_f32_16x16x32_bf16(ah, bh[m],
                                                            acc[j][m], 0, 0, 0);
        acc[j][m] = __builtin_amdgcn_mfma_f32_16x16x32_bf16(ah, bl[m],
                                                            acc[j][m], 0, 0, 0);
        acc[j][m] = __builtin_amdgcn_mfma_f32_16x16x32_bf16(al, bh[m],
                                                            acc[j][m], 0, 0, 0);
      }
    }
  }

  // ---- epilogue: D[m][n]: n = lane&15, m = (lane>>4)*4 + reg ----
  const int row0 = (lane >> 4) * 4;
  const int col  = lane & 15;
#pragma unroll
  for (int j = 0; j < 4; ++j)
#pragma unroll
    for (int m = 0; m < 4; ++m) {
#pragma unroll
      for (int r = 0; r < 4; ++r) {
        const int o = ot + j * 16 + row0 + r;
        const int p = pt + (wave * 4 + m) * 16 + col;
        Yb[(size_t)o * HWSZ + p] = acc[j][m][r];
      }
    }
}

// ---------------------------------------------------------------------------
// K2a: depthwise 3x3 conv for one 192-channel group (slice layout
// [b][192][HWSZ]). Writes windowed layout:
// Bw[((b*1024+win)*576 + gbase+gc)*64 + t].  (Verified: ~38 us/launch.)
// ---------------------------------------------------------------------------
__global__ __launch_bounds__(256) void dwconv_win(
    const float* __restrict__ qkv, const float* __restrict__ wdw,
    float* __restrict__ Bw, int gbase) {
  __shared__ float t[10][264];
  const int gc = blockIdx.x;     // 0..191 within slice
  const int h1 = blockIdx.y;     // 0..31
  const int b  = blockIdx.z;
  const int tid = threadIdx.x;
  const int r0 = h1 * 8 - 1;
  const float* src = qkv + ((size_t)b * 192 + gc) * HWSZ;

  for (int idx = tid; idx < 640; idx += 256) {
    const int row = idx >> 6, cv = idx & 63;
    const int gr = r0 + row;
    float4 v = make_float4(0.f, 0.f, 0.f, 0.f);
    if ((unsigned)gr < 256u) v = *(const float4*)(src + gr * 256 + cv * 4);
    *(float4*)&t[row][4 + cv * 4] = v;
  }
  if (tid < 10) { t[tid][3] = 0.f; t[tid][260] = 0.f; }
  __syncthreads();

  const float* w9 = wdw + (size_t)(gbase + gc) * 9;
  const float w0 = w9[0], w1 = w9[1], w2 = w9[2];
  const float w3 = w9[3], w4 = w9[4], w5 = w9[5];
  const float w6 = w9[6], w7 = w9[7], w8 = w9[8];

  const int c = tid;                  // spatial col 0..255
  const int wv = c >> 3, tt = c & 7;  // window-in-row, token-col
  float* rec = Bw + (((size_t)(b * 1024 + h1 * 32 + wv) * C3) + gbase + gc) * 64
               + tt;

  float x0 = t[0][c + 3], x1 = t[0][c + 4], x2 = t[0][c + 5];
  float y0 = t[1][c + 3], y1 = t[1][c + 4], y2 = t[1][c + 5];
#pragma unroll
  for (int rr = 1; rr <= 8; ++rr) {
    const float z0 = t[rr + 1][c + 3], z1 = t[rr + 1][c + 4],
                z2 = t[rr + 1][c + 5];
    const float res = x0 * w0 + x1 * w1 + x2 * w2
                    + y0 * w3 + y1 * w4 + y2 * w5
                    + z0 * w6 + z1 * w7 + z2 * w8;
    rec[(rr - 1) * 8] = res;
    x0 = y0; x1 = y1; x2 = y2;
    y0 = z0; y1 = z1; y2 = z2;
  }
}

// ---------------------------------------------------------------------------
// K2b: gate GEMM: gate[row][y] = GELU( sum_x V[row][x]*mlpw[y][x] + mlpb[y] )
// Writes GELU'd gate DIRECTLY into the yw buffer at the addresses attn_bw2
// will later read-multiply-overwrite.
// ---------------------------------------------------------------------------
__global__ __launch_bounds__(256) void gate_gemm(
    const float* __restrict__ Bw, const float* __restrict__ mlpw,
    const float* __restrict__ mlpb, float* __restrict__ gate) {
  __shared__ float VT[64 * 68];   // [x][row]
  __shared__ float WT[64 * 68];   // [x][y]
  const int blk = blockIdx.x;
  const int rec = blk / 3;        // b*1024+win  (0..2047)
  const int sub = blk - rec * 3;  // 64-row chunk within the 192 V rows
  const int tid = threadIdx.x;

  const float* vsrc = Bw + (size_t)rec * (C3 * 64) + (384 + sub * 64) * 64;
#pragma unroll
  for (int i = 0; i < 4; ++i) {
    const int f4 = tid + 256 * i;
    const int r = f4 >> 4, x0 = (f4 & 15) * 4;
    const float4 v = *(const float4*)(vsrc + r * 64 + x0);
    VT[(x0 + 0) * 68 + r] = v.x;
    VT[(x0 + 1) * 68 + r] = v.y;
    VT[(x0 + 2) * 68 + r] = v.z;
    VT[(x0 + 3) * 68 + r] = v.w;
    const float4 w = *(const float4*)(mlpw + r * 64 + x0);
    WT[(x0 + 0) * 68 + r] = w.x;
    WT[(x0 + 1) * 68 + r] = w.y;
    WT[(x0 + 2) * 68 + r] = w.z;
    WT[(x0 + 3) * 68 + r] = w.w;
  }
  __syncthreads();

  const int tx = tid & 15, ty = tid >> 4;
  float acc[4][4];
#pragma unroll
  for (int i = 0; i < 4; ++i)
#pragma unroll
    for (int j = 0; j < 4; ++j) acc[i][j] = 0.f;

  for (int x = 0; x < 64; ++x) {
    const float4 a4 = *(const float4*)&VT[x * 68 + ty * 4];
    const float4 b4 = *(const float4*)&WT[x * 68 + tx * 4];
    const float avr[4] = {a4.x, a4.y, a4.z, a4.w};
    const float bvr[4] = {b4.x, b4.y, b4.z, b4.w};
#pragma unroll
    for (int i = 0; i < 4; ++i)
#pragma unroll
      for (int j = 0; j < 4; ++j) acc[i][j] += avr[i] * bvr[j];
  }

  const float kE = 0.70710678118654752f;
  const float b0 = mlpb[tx * 4 + 0], b1 = mlpb[tx * 4 + 1];
  const float b2 = mlpb[tx * 4 + 2], b3 = mlpb[tx * 4 + 3];
#pragma unroll
  for (int i = 0; i < 4; ++i) {
    const int row = ty * 4 + i;   // V-channel within this 64-chunk
    float g0 = acc[i][0] + b0;
    float g1 = acc[i][1] + b1;
    float g2 = acc[i][2] + b2;
    float g3 = acc[i][3] + b3;
    g0 = 0.5f * g0 * (1.f + erff(g0 * kE));
    g1 = 0.5f * g1 * (1.f + erff(g1 * kE));
    g2 = 0.5f * g2 * (1.f + erff(g2 * kE));
    g3 = 0.5f * g3 * (1.f + erff(g3 * kE));
    float* dst = gate + ((size_t)rec * 192 + sub * 64 + row) * 64 + tx * 4;
    *(float4*)dst = make_float4(g0, g1, g2, g3);
  }
}

// ---------------------------------------------------------------------------
// K2c: windowed channel attention (gate precomputed).
// Compute phases VERBATIM from the harness-verified R0/R3 structure.
// ---------------------------------------------------------------------------
__global__ __launch_bounds__(256, 5) void attn_bw2(
    const float* __restrict__ Bw, const float* __restrict__ temp,
    float* __restrict__ yw) {
  __shared__ float dwv[64 * 97];
  __shared__ float attnS[32 * 33];
  __shared__ float scl[64];
  const int bid = blockIdx.x;
  const int b   = bid / 6144;
  const int rr  = bid % 6144;
  const int xcd = rr & 7;
  const int s   = rr >> 3;
  const int head = s % 6;
  const int wloc = s / 6;
  const int win  = xcd * 128 + wloc;
  const int tid = threadIdx.x;
  const int ch = tid >> 3;   // 0..31
  const int iy = tid & 7;    // 0..7

  {
    const float* rec = Bw + (size_t)(b * 1024 + win) * C3 * 64;
    const int t8 = iy * 8;
#pragma unroll
    for (int g = 0; g < 3; ++g) {
      const float* sp = rec + (size_t)(g * 192 + head * 32 + ch) * 64 + t8;
      const float4 v0 = *(const float4*)sp;
      const float4 v1 = *(const float4*)(sp + 4);
      const int gc = g * 32 + ch;
      dwv[(t8 + 0) * 97 + gc] = v0.x;
      dwv[(t8 + 1) * 97 + gc] = v0.y;
      dwv[(t8 + 2) * 97 + gc] = v0.z;
      dwv[(t8 + 3) * 97 + gc] = v0.w;
      dwv[(t8 + 4) * 97 + gc] = v1.x;
      dwv[(t8 + 5) * 97 + gc] = v1.y;
      dwv[(t8 + 6) * 97 + gc] = v1.z;
      dwv[(t8 + 7) * 97 + gc] = v1.w;
    }
  }
  __syncthreads();

  if (tid < 64) {
    float ss = 0.f;
    for (int t = 0; t < 64; ++t) {
      const float v = dwv[t * 97 + tid];
      ss += v * v;
    }
    scl[tid] = 1.f / fmaxf(sqrtf(ss), 1e-12f);
  }
  __syncthreads();

  {
    const int c = tid >> 3, m = tid & 7;
    float sa[4] = {0.f, 0.f, 0.f, 0.f};
    for (int t = 0; t < 64; ++t) {
      const float qv = dwv[t * 97 + c];
#pragma unroll
      for (int j = 0; j < 4; ++j) sa[j] += qv * dwv[t * 97 + 32 + m * 4 + j];
    }
    const float qs = scl[c] * temp[head];
#pragma unroll
    for (int j = 0; j < 4; ++j) sa[j] *= qs * scl[32 + m * 4 + j];
    float mx = fmaxf(fmaxf(sa[0], sa[1]), fmaxf(sa[2], sa[3]));
    for (int off = 1; off < 8; off <<= 1) mx = fmaxf(mx, __shfl_xor(mx, off, 8));
    float sum = 0.f;
#pragma unroll
    for (int j = 0; j < 4; ++j) {
      sa[j] = expf(sa[j] - mx);
      sum += sa[j];
    }
    for (int off = 1; off < 8; off <<= 1) sum += __shfl_xor(sum, off, 8);
    const float inv = 1.f / sum;
#pragma unroll
    for (int j = 0; j < 4; ++j) attnS[c * 33 + m * 4 + j] = sa[j] * inv;
  }
  __syncthreads();

  {
    const int c = ch;
    float* dst = yw + (((size_t)(b * 1024 + win) * 192 + head * 32 + c) * 64
                       + iy * 8);
    const float4 gA = *(const float4*)dst;
    const float4 gB = *(const float4*)(dst + 4);
    float ov[8] = {0.f, 0.f, 0.f, 0.f, 0.f, 0.f, 0.f, 0.f};
    const int tb = iy * 8 * 97 + 64;
    for (int d = 0; d < 32; ++d) {
      const float a = attnS[c * 33 + d];
#pragma unroll
      for (int j = 0; j < 8; ++j) ov[j] += a * dwv[tb + j * 97 + d];
    }
    *(float4*)dst       = make_float4(ov[0] * gA.x, ov[1] * gA.y,
                                      ov[2] * gA.z, ov[3] * gA.w);
    *(float4*)(dst + 4) = make_float4(ov[4] * gB.x, ov[5] * gB.y,
                                      ov[6] * gB.z, ov[7] * gB.w);
  }
}

// ---------------------------------------------------------------------------
// K3: proj GEMM reading windowed yw, writing spatial out (+bias).
// ---------------------------------------------------------------------------
__global__ __launch_bounds__(256) void proj_gemm(
    const float* __restrict__ yw, const float* __restrict__ Wm,
    const float* __restrict__ bias, float* __restrict__ out) {
  __shared__ float As[16][68];
  __shared__ float Bs[16][256];
  const int ptile = blockIdx.x;
  const int ot = blockIdx.y * 64;
  const int b  = blockIdx.z;
  const int h1 = ptile >> 3, w4 = ptile & 7;
  const int win0 = h1 * 32 + w4 * 4;
  const int tid = threadIdx.x;
  const int tx = tid & 15, ty = tid >> 4;
  const int oA = tid >> 2, kA = (tid & 3) * 4;
  float acc[4][16];
#pragma unroll
  for (int i = 0; i < 4; ++i)
#pragma unroll
    for (int j = 0; j < 16; ++j) acc[i][j] = 0.f;

  const float* ywb = yw + (size_t)(b * 1024 + win0) * 192 * 64;
  for (int k0 = 0; k0 < 192; k0 += 16) {
    float4 av = *(const float4*)(Wm + (size_t)(ot + oA) * 192 + k0 + kA);
    As[kA + 0][oA] = av.x;
    As[kA + 1][oA] = av.y;
    As[kA + 2][oA] = av.z;
    As[kA + 3][oA] = av.w;
#pragma unroll
    for (int i = 0; i < 4; ++i) {
      const int f4 = tid + 256 * i;
      const int k = f4 >> 6, p4 = f4 & 63;
      const int wv = p4 >> 4, tt = (p4 & 15) * 4;
      *(float4*)&Bs[k][p4 * 4] =
          *(const float4*)(ywb + ((size_t)wv * 192 + k0 + k) * 64 + tt);
    }
    __syncthreads();
#pragma unroll
    for (int k = 0; k < 16; ++k) {
      const float4 a4 = *(const float4*)&As[k][ty * 4];
      const float4 b0 = *(const float4*)&Bs[k][tx * 4];
      const float4 b1 = *(const float4*)&Bs[k][64 + tx * 4];
      const float4 b2 = *(const float4*)&Bs[k][128 + tx * 4];
      const float4 b3 = *(const float4*)&Bs[k][192 + tx * 4];
      const float avr[4] = {a4.x, a4.y, a4.z, a4.w};
      const float bvr[16] = {b0.x, b0.y, b0.z, b0.w,
                             b1.x, b1.y, b1.z, b1.w,
                             b2.x, b2.y, b2.z, b2.w,
                             b3.x, b3.y, b3.z, b3.w};
#pragma unroll
      for (int i = 0; i < 4; ++i)
#pragma unroll
        for (int j = 0; j < 16; ++j) acc[i][j] += avr[i] * bvr[j];
    }
    __syncthreads();
  }
  const int colbase = w4 * 32;
#pragma unroll
  for (int i = 0; i < 4; ++i) {
    const int o = ot + ty * 4 + i;
    const float bv = bias[o];
    float* ob = out + ((size_t)(b * 192 + o) * 256 + h1 * 8) * 256 + colbase;
#pragma unroll
    for (int j = 0; j < 16; ++j) {
      const int p = (j >> 2) * 64 + tx * 4 + (j & 3);
      const int wv = p >> 6;
      const int t = p & 63;
      ob[(t >> 3) * 256 + wv * 8 + (t & 7)] = acc[i][j] + bv;
    }
  }
}

extern "C" void kernel_launch(void* const* d_in, const int* in_sizes, int n_in,
                              void* d_out, int out_size, void* d_ws, size_t ws_size,
                              hipStream_t stream) {
  const float* x           = (const float*)d_in[0];
  const float* w_qkv       = (const float*)d_in[1];
  const float* w_dw        = (const float*)d_in[2];
  const float* temperature = (const float*)d_in[3];
  const float* mlp_w       = (const float*)d_in[4];
  const float* mlp_b       = (const float*)d_in[5];
  const float* proj_w      = (const float*)d_in[6];
  const float* proj_b      = (const float*)d_in[7];
  float* out = (float*)d_out;

  // Workspace (402.65 MB, verified footprint):
  //   [0 .. 25165824)         slice: spatial conv1x1 output for one 192-ch
  //                           group; reused as gate/yw buffer afterwards.
  //   [25165824 .. 100663296) Bw: windowed dw-qkv, all 576 channels.
  float* slice = (float*)d_ws;
  float* Bw    = slice + (size_t)2 * 192 * HWSZ;   // +25165824

  for (int g = 0; g < 3; ++g) {
    conv1x1_mfma<<<dim3(256, 3, 2), 256, 0, stream>>>(
        x, w_qkv + (size_t)g * 192 * CIN, slice);
    dwconv_win<<<dim3(192, 32, 2), 256, 0, stream>>>(
        slice, w_dw, Bw, g * 192);
  }
  // gate = GELU(V @ mlp^T + b) written into the yw buffer (slice)
  gate_gemm<<<dim3(6144), 256, 0, stream>>>(Bw, mlp_w, mlp_b, slice);
  // attn reads gate from slice, multiplies, overwrites in place
  attn_bw2<<<dim3(12288), 256, 0, stream>>>(Bw, temperature, slice);
  proj_gemm<<<dim3(256, 3, 2), 256, 0, stream>>>(slice, proj_w, proj_b, out);
}